// Round 1
// baseline (3746.824 us; speedup 1.0000x reference)
//
#include <hip/hip_runtime.h>
#include <math.h>

#define Bq    1024
#define Nn    29
#define DIMq  64
#define Kq    8
#define MD    16
#define EIN   129
#define EH    258   // 2*EIN
#define CHID  64    // 4*MD
#define NIN   80    // DIM+MD
#define NHID  128   // 2*DIM
#define DEPTHq 4

__device__ __forceinline__ float silu_f(float x) {
    return x / (1.0f + expf(-x));
}

__global__ void k_init(const int* __restrict__ tokens,
                       const float* __restrict__ temb,
                       const float* __restrict__ pemb,
                       float* __restrict__ feats) {
    int o = blockIdx.x * 256 + threadIdx.x;
    if (o >= Bq * Nn * DIMq) return;
    int d = o & (DIMq - 1);
    int bn = o >> 6;            // /DIMq
    int n = bn % Nn;
    int t = tokens[bn];
    feats[o] = temb[t * DIMq + d] + pemb[n * DIMq + d];
}

__global__ __launch_bounds__(256)
void k_layer(const float* __restrict__ feats_in, const float* __restrict__ coors_in,
             float* __restrict__ feats_out, float* __restrict__ coors_out,
             const float* __restrict__ ew1, const float* __restrict__ eb1,
             const float* __restrict__ ew2, const float* __restrict__ eb2,
             const float* __restrict__ cw1, const float* __restrict__ cb1,
             const float* __restrict__ cw2, const float* __restrict__ cb2,
             const float* __restrict__ csc,
             const float* __restrict__ lng, const float* __restrict__ lnb,
             const float* __restrict__ nw1, const float* __restrict__ nb1,
             const float* __restrict__ nw2, const float* __restrict__ nb2,
             int layer) {
    ew1 += layer * EIN * EH;  eb1 += layer * EH;
    ew2 += layer * EH * MD;   eb2 += layer * MD;
    cw1 += layer * MD * CHID; cb1 += layer * CHID;
    cw2 += layer * CHID;      cb2 += layer;
    lng += layer * DIMq;      lnb += layer * DIMq;
    nw1 += layer * NIN * NHID; nb1 += layer * NHID;
    nw2 += layer * NHID * DIMq; nb2 += layer * DIMq;
    const float cscale = csc[layer];

    __shared__ float s_f[Nn][DIMq];
    __shared__ float s_c[Nn][3];
    __shared__ float s_d2[Nn][Nn];
    __shared__ int   s_idx[Nn][Kq];
    __shared__ float s_dk[Nn][Kq];
    __shared__ float s_p1[Nn][EH];
    __shared__ float s_fj[Kq][DIMq];
    __shared__ float s_rel[Kq][3];
    __shared__ float s_h1[Kq][EH];
    __shared__ float s_mc[Kq][MD];
    __shared__ float s_mi[Nn][MD];
    __shared__ float s_ch[Kq][CHID];
    __shared__ float s_cw[Kq];
    __shared__ float s_ni[Nn][NIN];
    __shared__ float s_nh[Nn][NHID];

    const int b = blockIdx.x;
    const int tid = threadIdx.x;

    // ---- load feats + coords into LDS ----
    const float* fb = feats_in + (size_t)b * Nn * DIMq;
    for (int o = tid; o < Nn * DIMq; o += 256) s_f[0][o] = fb[o];
    for (int o = tid; o < Nn * 3; o += 256) s_c[0][o] = coors_in[(size_t)b * Nn * 3 + o];
    __syncthreads();

    // ---- all-pairs squared distances (match reference rounding: no FMA) ----
    for (int o = tid; o < Nn * Nn; o += 256) {
        int i = o / Nn, j = o % Nn;
        float dx = __fsub_rn(s_c[i][0], s_c[j][0]);
        float dy = __fsub_rn(s_c[i][1], s_c[j][1]);
        float dz = __fsub_rn(s_c[i][2], s_c[j][2]);
        s_d2[i][j] = __fadd_rn(__fadd_rn(__fmul_rn(dx, dx), __fmul_rn(dy, dy)),
                               __fmul_rn(dz, dz));
    }
    __syncthreads();

    // ---- stable K-nearest selection (matches top_k tie semantics) ----
    if (tid < Nn) {
        unsigned chosen = 0;
        for (int r = 0; r < Kq; ++r) {
            float best = 3.4e38f; int bj = 0;
            for (int j = 0; j < Nn; ++j) {
                if ((chosen >> j) & 1u) continue;
                float v = s_d2[tid][j];
                if (v < best) { best = v; bj = j; }
            }
            chosen |= 1u << bj;
            s_idx[tid][r] = bj;
            s_dk[tid][r] = best;
        }
    }

    // ---- part1: f_i @ ew1[0:64]  (shared across the node's K edges) ----
    for (int c = tid; c < EH; c += 256) {
        float acc[Nn];
        #pragma unroll
        for (int n = 0; n < Nn; ++n) acc[n] = 0.f;
        for (int i = 0; i < DIMq; ++i) {
            float w = ew1[i * EH + c];
            #pragma unroll
            for (int n = 0; n < Nn; ++n) acc[n] = fmaf(s_f[n][i], w, acc[n]);
        }
        #pragma unroll
        for (int n = 0; n < Nn; ++n) s_p1[n][c] = acc[n];
    }
    __syncthreads();

    // ---- per-node edge processing ----
    for (int n = 0; n < Nn; ++n) {
        // gather neighbor feats + rel vectors
        for (int o = tid; o < Kq * DIMq; o += 256) {
            int k = o >> 6, d = o & 63;
            s_fj[k][d] = s_f[s_idx[n][k]][d];
        }
        if (tid < Kq * 3) {
            int k = tid / 3, c = tid % 3;
            s_rel[k][c] = __fsub_rn(s_c[n][c], s_c[s_idx[n][k]][c]);
        }
        __syncthreads();

        // h1 = silu(edge_in @ ew1 + eb1), per column c, all 8 edges
        for (int c = tid; c < EH; c += 256) {
            float accs[Kq];
            #pragma unroll
            for (int k = 0; k < Kq; ++k) accs[k] = 0.f;
            for (int i = 0; i < DIMq; ++i) {
                float w = ew1[(DIMq + i) * EH + c];
                #pragma unroll
                for (int k = 0; k < Kq; ++k) accs[k] = fmaf(s_fj[k][i], w, accs[k]);
            }
            float wd = ew1[128 * EH + c];
            float base = s_p1[n][c] + eb1[c];
            #pragma unroll
            for (int k = 0; k < Kq; ++k)
                s_h1[k][c] = silu_f(fmaf(s_dk[n][k], wd, base + accs[k]));
        }
        __syncthreads();

        // m_ij = silu(h1 @ ew2 + eb2)
        if (tid < Kq * MD) {
            int k = tid >> 4, c2 = tid & 15;
            float acc = eb2[c2];
            for (int c = 0; c < EH; ++c) acc = fmaf(s_h1[k][c], ew2[c * MD + c2], acc);
            s_mc[k][c2] = silu_f(acc);
        }
        __syncthreads();

        // coors hidden = silu(m @ cw1 + cb1)
        if (tid < Kq * CHID) {
            int k = tid >> 6, c = tid & 63;
            float acc = cb1[c];
            #pragma unroll
            for (int i = 0; i < MD; ++i) acc = fmaf(s_mc[k][i], cw1[i * CHID + c], acc);
            s_ch[k][c] = silu_f(acc);
        }
        __syncthreads();

        // coor_w (clamped)
        if (tid < Kq) {
            float acc = cb2[0];
            for (int i = 0; i < CHID; ++i) acc = fmaf(s_ch[tid][i], cw2[i], acc);
            acc = fminf(fmaxf(acc, -2.f), 2.f);
            s_cw[tid] = acc;
        }
        __syncthreads();

        // m_i pool + coords update
        if (tid < MD) {
            float acc = 0.f;
            #pragma unroll
            for (int k = 0; k < Kq; ++k) acc += s_mc[k][tid];
            s_mi[n][tid] = acc;
        }
        if (tid < 3) {
            float acc = 0.f;
            for (int k = 0; k < Kq; ++k) {
                float nrm = sqrtf(s_dk[n][k]);
                float rn = s_rel[k][tid] / fmaxf(nrm, 1e-8f) * cscale;
                acc = fmaf(s_cw[k], rn, acc);
            }
            coors_out[((size_t)b * Nn + n) * 3 + tid] = s_c[n][tid] + acc;
        }
        __syncthreads();
    }

    // ---- node MLP: LayerNorm + concat(m_i) -> 128 -> 64 + residual ----
    if (tid < Nn) {
        float mu = 0.f;
        for (int d = 0; d < DIMq; ++d) mu += s_f[tid][d];
        mu *= (1.0f / 64.0f);
        float var = 0.f;
        for (int d = 0; d < DIMq; ++d) { float t = s_f[tid][d] - mu; var = fmaf(t, t, var); }
        var *= (1.0f / 64.0f);
        float rs = rsqrtf(var + 1e-5f);
        for (int d = 0; d < DIMq; ++d)
            s_ni[tid][d] = (s_f[tid][d] - mu) * rs * lng[d] + lnb[d];
        for (int c2 = 0; c2 < MD; ++c2) s_ni[tid][DIMq + c2] = s_mi[tid][c2];
    }
    __syncthreads();

    for (int o = tid; o < Nn * NHID; o += 256) {
        int n = o >> 7, c = o & 127;
        float acc = nb1[c];
        for (int i = 0; i < NIN; ++i) acc = fmaf(s_ni[n][i], nw1[i * NHID + c], acc);
        s_nh[n][c] = silu_f(acc);
    }
    __syncthreads();

    for (int o = tid; o < Nn * DIMq; o += 256) {
        int n = o >> 6, c = o & 63;
        float acc = nb2[c];
        for (int i = 0; i < NHID; ++i) acc = fmaf(s_nh[n][i], nw2[i * DIMq + c], acc);
        feats_out[((size_t)b * Nn + n) * DIMq + c] = acc + s_f[n][c];
    }
}

__global__ __launch_bounds__(64)
void k_read(const float* __restrict__ feats,
            const float* __restrict__ rw1, const float* __restrict__ rb1,
            const float* __restrict__ rw2, const float* __restrict__ rb2,
            float* __restrict__ out) {
    __shared__ float s_mol[DIMq];
    const int b = blockIdx.x, t = threadIdx.x;
    float acc = 0.f;
    for (int n = 0; n < Nn; ++n) acc += feats[((size_t)b * Nn + n) * DIMq + t];
    s_mol[t] = acc / 29.0f;
    __syncthreads();
    float a2 = rb1[t];
    for (int i = 0; i < DIMq; ++i) a2 = fmaf(s_mol[i], rw1[i * DIMq + t], a2);
    float part = silu_f(a2) * rw2[t];
    #pragma unroll
    for (int off = 32; off > 0; off >>= 1) part += __shfl_down(part, off);
    if (t == 0) out[b] = part + rb2[0];
}

extern "C" void kernel_launch(void* const* d_in, const int* in_sizes, int n_in,
                              void* d_out, int out_size, void* d_ws, size_t ws_size,
                              hipStream_t stream) {
    const int*   tokens = (const int*)d_in[0];
    const float* coords = (const float*)d_in[1];
    // d_in[2] = mask : all-True in this problem; reference reduces to unmasked path
    const float* temb = (const float*)d_in[3];
    const float* pemb = (const float*)d_in[4];
    const float* ew1 = (const float*)d_in[5];
    const float* eb1 = (const float*)d_in[6];
    const float* ew2 = (const float*)d_in[7];
    const float* eb2 = (const float*)d_in[8];
    const float* cw1 = (const float*)d_in[9];
    const float* cb1 = (const float*)d_in[10];
    const float* cw2 = (const float*)d_in[11];
    const float* cb2 = (const float*)d_in[12];
    const float* csc = (const float*)d_in[13];
    const float* lng = (const float*)d_in[14];
    const float* lnb = (const float*)d_in[15];
    const float* nw1 = (const float*)d_in[16];
    const float* nb1 = (const float*)d_in[17];
    const float* nw2 = (const float*)d_in[18];
    const float* nb2 = (const float*)d_in[19];
    const float* rw1 = (const float*)d_in[20];
    const float* rb1 = (const float*)d_in[21];
    const float* rw2 = (const float*)d_in[22];
    const float* rb2 = (const float*)d_in[23];

    float* fA = (float*)d_ws;
    float* fB = fA + (size_t)Bq * Nn * DIMq;
    float* cA = fB + (size_t)Bq * Nn * DIMq;
    float* cB = cA + (size_t)Bq * Nn * 3;

    k_init<<<(Bq * Nn * DIMq + 255) / 256, 256, 0, stream>>>(tokens, temb, pemb, fA);

    const float* fin = fA;
    const float* cin = coords;
    float* fbufs[2] = {fB, fA};
    float* cbufs[2] = {cA, cB};
    for (int l = 0; l < DEPTHq; ++l) {
        float* fout = fbufs[l & 1];
        float* cout = cbufs[l & 1];
        k_layer<<<Bq, 256, 0, stream>>>(fin, cin, fout, cout,
                                        ew1, eb1, ew2, eb2,
                                        cw1, cb1, cw2, cb2, csc,
                                        lng, lnb, nw1, nb1, nw2, nb2, l);
        fin = fout;
        cin = cout;
    }

    k_read<<<Bq, 64, 0, stream>>>(fin, rw1, rb1, rw2, rb2, (float*)d_out);
}

// Round 2
// 1616.933 us; speedup vs baseline: 2.3172x; 2.3172x over previous
//
#include <hip/hip_runtime.h>
#include <math.h>

#define Bq    1024
#define Nn    29
#define DIMq  64
#define Kq    8
#define MD    16
#define EIN   129
#define EH    258   // 2*EIN
#define CHID  64    // 4*MD
#define NIN   80    // DIM+MD
#define NHID  128   // 2*DIM
#define DEPTHq 4
#define WROW  68    // transposed ew1 row stride (64 fj + 1 dist + 3 pad, 16B aligned)

__device__ __forceinline__ float silu_f(float x) {
    return x / (1.0f + expf(-x));
}

__global__ void k_init(const int* __restrict__ tokens,
                       const float* __restrict__ temb,
                       const float* __restrict__ pemb,
                       float* __restrict__ feats) {
    int o = blockIdx.x * 256 + threadIdx.x;
    if (o >= Bq * Nn * DIMq) return;
    int d = o & (DIMq - 1);
    int bn = o >> 6;
    int n = bn % Nn;
    int t = tokens[bn];
    feats[o] = temb[t * DIMq + d] + pemb[n * DIMq + d];
}

// one-time weight transposes into workspace:
//  ew1T[l][c][WROW]: [0..63] = ew1[l][64+i][c] (f_j half), [64] = ew1[l][128][c] (dist row)
//  cw1T[l][cc][16]:  cw1[l][i][cc]
__global__ void k_tw(const float* __restrict__ ew1, const float* __restrict__ cw1,
                     float* __restrict__ ew1T, float* __restrict__ cw1T) {
    int o = blockIdx.x * 256 + threadIdx.x;
    const int n1 = DEPTHq * EH * WROW;
    if (o < n1) {
        int q = o % WROW; int rem = o / WROW; int c = rem % EH; int l = rem / EH;
        float v = 0.f;
        if (q < 64)       v = ew1[(size_t)l * EIN * EH + (size_t)(64 + q) * EH + c];
        else if (q == 64) v = ew1[(size_t)l * EIN * EH + (size_t)128 * EH + c];
        ew1T[o] = v;
    } else {
        int o2 = o - n1;
        if (o2 < DEPTHq * CHID * MD) {
            int i = o2 % MD; int rem = o2 / MD; int cc = rem % CHID; int l = rem / CHID;
            cw1T[o2] = cw1[(size_t)l * MD * CHID + (size_t)i * CHID + cc];
        }
    }
}

__global__ __launch_bounds__(256, 3)
void k_layer(const float* __restrict__ feats_in, const float* __restrict__ coors_in,
             float* __restrict__ feats_out, float* __restrict__ coors_out,
             const float* __restrict__ ew1, const float* __restrict__ eb1,
             const float* __restrict__ ew1T,
             const float* __restrict__ ew2, const float* __restrict__ eb2,
             const float* __restrict__ cw1T, const float* __restrict__ cb1,
             const float* __restrict__ cw2, const float* __restrict__ cb2,
             const float* __restrict__ csc,
             const float* __restrict__ lng, const float* __restrict__ lnb,
             const float* __restrict__ nw1, const float* __restrict__ nb1,
             const float* __restrict__ nw2, const float* __restrict__ nb2,
             int layer) {
    ew1  += (size_t)layer * EIN * EH;   eb1 += layer * EH;
    ew1T += (size_t)layer * EH * WROW;
    ew2  += (size_t)layer * EH * MD;    eb2 += layer * MD;
    cw1T += (size_t)layer * CHID * MD;  cb1 += layer * CHID;
    cw2  += layer * CHID;               cb2 += layer;
    lng  += layer * DIMq;               lnb += layer * DIMq;
    nw1  += (size_t)layer * NIN * NHID; nb1 += layer * NHID;
    nw2  += (size_t)layer * NHID * DIMq; nb2 += layer * DIMq;
    const float cscale = csc[layer];

    __shared__ float s_f[Nn][65];          // padded: bank-conflict-free row reads
    __shared__ float s_c[Nn][3];
    __shared__ int   s_idx[Nn][Kq];
    __shared__ float s_dk[Nn][Kq];
    __shared__ union RegB {                // d2 dead after kNN -> reuse for cw/mi
        float d2[Nn][Nn];
        struct { float cw[232]; float mi[Nn][MD]; } e;
    } ub;
    __shared__ union RegC {                // p1 dead after edge loop -> reuse for node MLP
        float p1[Nn][EH];
        struct { float ni[Nn][NIN]; float nh[Nn][NHID]; } np;
    } uc;

    const int b = blockIdx.x;
    const int tid = threadIdx.x;

    // ---- load feats + coords ----
    const float* fb = feats_in + (size_t)b * Nn * DIMq;
    for (int o = tid; o < Nn * DIMq; o += 256) s_f[o >> 6][o & 63] = fb[o];
    for (int o = tid; o < Nn * 3; o += 256) s_c[0][o] = coors_in[(size_t)b * Nn * 3 + o];
    __syncthreads();

    // ---- all-pairs squared distances (exact rounding: matches kNN selection) ----
    for (int o = tid; o < Nn * Nn; o += 256) {
        int i = o / Nn, j = o % Nn;
        float dx = __fsub_rn(s_c[i][0], s_c[j][0]);
        float dy = __fsub_rn(s_c[i][1], s_c[j][1]);
        float dz = __fsub_rn(s_c[i][2], s_c[j][2]);
        ub.d2[i][j] = __fadd_rn(__fadd_rn(__fmul_rn(dx, dx), __fmul_rn(dy, dy)),
                                __fmul_rn(dz, dz));
    }

    // ---- part1: p1[n][c] = eb1[c] + f_i[n] . ew1[0:64][c]  (shared over K edges) ----
    {
        int c = tid;
        for (int rep = 0; rep < 2; ++rep) {
            if (rep == 1) { if (tid < 254) break; c = tid + 2; }  // cols 256,257
            float acc[Nn];
            #pragma unroll
            for (int n2 = 0; n2 < Nn; ++n2) acc[n2] = eb1[c];
            for (int i = 0; i < DIMq; ++i) {
                float w = ew1[i * EH + c];
                #pragma unroll
                for (int n2 = 0; n2 < Nn; ++n2) acc[n2] = fmaf(s_f[n2][i], w, acc[n2]);
            }
            #pragma unroll
            for (int n2 = 0; n2 < Nn; ++n2) uc.p1[n2][c] = acc[n2];
        }
    }
    __syncthreads();

    // ---- stable K-nearest (matches top_k(-d2) tie semantics) ----
    if (tid < Nn) {
        unsigned chosen = 0;
        for (int r = 0; r < Kq; ++r) {
            float best = 3.4e38f; int bj = 0;
            for (int j = 0; j < Nn; ++j) {
                if ((chosen >> j) & 1u) continue;
                float v = ub.d2[tid][j];
                if (v < best) { best = v; bj = j; }
            }
            chosen |= 1u << bj;
            s_idx[tid][r] = bj;
            s_dk[tid][r] = best;
        }
    }
    __syncthreads();

    // ---- fused edge MLP: one lane per edge (232 edges) ----
    if (tid < Nn * Kq) {
        const int e = tid, n = e >> 3, k = e & 7;
        const int jj = s_idx[n][k];
        const float dd = s_dk[n][k];

        float4 fj4[16];
        #pragma unroll
        for (int q = 0; q < 16; ++q)
            fj4[q] = make_float4(s_f[jj][4*q], s_f[jj][4*q+1], s_f[jj][4*q+2], s_f[jj][4*q+3]);

        float m[MD];
        #pragma unroll
        for (int q = 0; q < MD; ++q) m[q] = 0.f;

        #pragma unroll 2
        for (int c = 0; c < EH; ++c) {
            const float4* wr = (const float4*)(ew1T + c * WROW);
            float s0 = 0.f, s1 = 0.f, s2 = 0.f, s3 = 0.f;
            #pragma unroll
            for (int q = 0; q < 16; ++q) {
                float4 w = wr[q];
                s0 = fmaf(fj4[q].x, w.x, s0);
                s1 = fmaf(fj4[q].y, w.y, s1);
                s2 = fmaf(fj4[q].z, w.z, s2);
                s3 = fmaf(fj4[q].w, w.w, s3);
            }
            float wd = wr[16].x;   // dist-row weight at [64]
            float acc = uc.p1[n][c] + dd * wd + ((s0 + s1) + (s2 + s3));
            float h = silu_f(acc);
            const float4* w2 = (const float4*)(ew2 + c * MD);
            float4 a0 = w2[0], a1 = w2[1], a2 = w2[2], a3 = w2[3];
            m[0]  = fmaf(h, a0.x, m[0]);  m[1]  = fmaf(h, a0.y, m[1]);
            m[2]  = fmaf(h, a0.z, m[2]);  m[3]  = fmaf(h, a0.w, m[3]);
            m[4]  = fmaf(h, a1.x, m[4]);  m[5]  = fmaf(h, a1.y, m[5]);
            m[6]  = fmaf(h, a1.z, m[6]);  m[7]  = fmaf(h, a1.w, m[7]);
            m[8]  = fmaf(h, a2.x, m[8]);  m[9]  = fmaf(h, a2.y, m[9]);
            m[10] = fmaf(h, a2.z, m[10]); m[11] = fmaf(h, a2.w, m[11]);
            m[12] = fmaf(h, a3.x, m[12]); m[13] = fmaf(h, a3.y, m[13]);
            m[14] = fmaf(h, a3.z, m[14]); m[15] = fmaf(h, a3.w, m[15]);
        }
        #pragma unroll
        for (int q = 0; q < MD; ++q) m[q] = silu_f(eb2[q] + m[q]);

        // coor MLP per edge: cw = clamp((silu(m@cw1+cb1))@cw2 + cb2)
        float cwacc = cb2[0];
        for (int cc = 0; cc < CHID; ++cc) {
            const float4* wr = (const float4*)(cw1T + cc * MD);
            float4 w0 = wr[0], w1 = wr[1], w2v = wr[2], w3 = wr[3];
            float hh = cb1[cc];
            hh = fmaf(m[0],  w0.x, hh); hh = fmaf(m[1],  w0.y, hh);
            hh = fmaf(m[2],  w0.z, hh); hh = fmaf(m[3],  w0.w, hh);
            hh = fmaf(m[4],  w1.x, hh); hh = fmaf(m[5],  w1.y, hh);
            hh = fmaf(m[6],  w1.z, hh); hh = fmaf(m[7],  w1.w, hh);
            hh = fmaf(m[8],  w2v.x, hh); hh = fmaf(m[9],  w2v.y, hh);
            hh = fmaf(m[10], w2v.z, hh); hh = fmaf(m[11], w2v.w, hh);
            hh = fmaf(m[12], w3.x, hh); hh = fmaf(m[13], w3.y, hh);
            hh = fmaf(m[14], w3.z, hh); hh = fmaf(m[15], w3.w, hh);
            hh = silu_f(hh);
            cwacc = fmaf(hh, cw2[cc], cwacc);
        }
        cwacc = fminf(fmaxf(cwacc, -2.f), 2.f);
        ub.e.cw[e] = cwacc;

        // m_i pool over the node's 8 edges = 8 consecutive lanes (8 | 64)
        #pragma unroll
        for (int q = 0; q < MD; ++q) {
            float v = m[q];
            v += __shfl_xor(v, 1);
            v += __shfl_xor(v, 2);
            v += __shfl_xor(v, 4);
            if (k == 0) ub.e.mi[n][q] = v;
        }
    }
    __syncthreads();

    // ---- coords update (87 lanes) + LayerNorm/node-input build (29 lanes) ----
    if (tid < Nn * 3) {
        int n2 = tid / 3, cix = tid % 3;
        float acc = 0.f;
        for (int k2 = 0; k2 < Kq; ++k2) {
            int j2 = s_idx[n2][k2];
            float nrm = sqrtf(s_dk[n2][k2]);
            float rel = __fsub_rn(s_c[n2][cix], s_c[j2][cix]);
            float rn = rel / fmaxf(nrm, 1e-8f) * cscale;
            acc = fmaf(ub.e.cw[n2 * Kq + k2], rn, acc);
        }
        coors_out[((size_t)b * Nn + n2) * 3 + cix] = s_c[n2][cix] + acc;
    }
    if (tid < Nn) {
        float mu = 0.f;
        for (int d = 0; d < DIMq; ++d) mu += s_f[tid][d];
        mu *= (1.0f / 64.0f);
        float var = 0.f;
        for (int d = 0; d < DIMq; ++d) { float t = s_f[tid][d] - mu; var = fmaf(t, t, var); }
        var *= (1.0f / 64.0f);
        float rs = rsqrtf(var + 1e-5f);
        for (int d = 0; d < DIMq; ++d)
            uc.np.ni[tid][d] = (s_f[tid][d] - mu) * rs * lng[d] + lnb[d];
        for (int c2 = 0; c2 < MD; ++c2) uc.np.ni[tid][DIMq + c2] = ub.e.mi[tid][c2];
    }
    __syncthreads();

    // ---- node MLP hidden ----
    for (int o = tid; o < Nn * NHID; o += 256) {
        int n2 = o >> 7, c = o & 127;
        float acc = nb1[c];
        for (int i = 0; i < NIN; ++i) acc = fmaf(uc.np.ni[n2][i], nw1[i * NHID + c], acc);
        uc.np.nh[n2][c] = silu_f(acc);
    }
    __syncthreads();

    // ---- node MLP out + residual ----
    for (int o = tid; o < Nn * DIMq; o += 256) {
        int n2 = o >> 6, c = o & 63;
        float acc = nb2[c];
        for (int i = 0; i < NHID; ++i) acc = fmaf(uc.np.nh[n2][i], nw2[i * DIMq + c], acc);
        feats_out[((size_t)b * Nn + n2) * DIMq + c] = acc + s_f[n2][c];
    }
}

__global__ __launch_bounds__(64)
void k_read(const float* __restrict__ feats,
            const float* __restrict__ rw1, const float* __restrict__ rb1,
            const float* __restrict__ rw2, const float* __restrict__ rb2,
            float* __restrict__ out) {
    __shared__ float s_mol[DIMq];
    const int b = blockIdx.x, t = threadIdx.x;
    float acc = 0.f;
    for (int n = 0; n < Nn; ++n) acc += feats[((size_t)b * Nn + n) * DIMq + t];
    s_mol[t] = acc / 29.0f;
    __syncthreads();
    float a2 = rb1[t];
    for (int i = 0; i < DIMq; ++i) a2 = fmaf(s_mol[i], rw1[i * DIMq + t], a2);
    float part = silu_f(a2) * rw2[t];
    #pragma unroll
    for (int off = 32; off > 0; off >>= 1) part += __shfl_down(part, off);
    if (t == 0) out[b] = part + rb2[0];
}

extern "C" void kernel_launch(void* const* d_in, const int* in_sizes, int n_in,
                              void* d_out, int out_size, void* d_ws, size_t ws_size,
                              hipStream_t stream) {
    const int*   tokens = (const int*)d_in[0];
    const float* coords = (const float*)d_in[1];
    // d_in[2] = mask : all-True in this problem
    const float* temb = (const float*)d_in[3];
    const float* pemb = (const float*)d_in[4];
    const float* ew1 = (const float*)d_in[5];
    const float* eb1 = (const float*)d_in[6];
    const float* ew2 = (const float*)d_in[7];
    const float* eb2 = (const float*)d_in[8];
    const float* cw1 = (const float*)d_in[9];
    const float* cb1 = (const float*)d_in[10];
    const float* cw2 = (const float*)d_in[11];
    const float* cb2 = (const float*)d_in[12];
    const float* csc = (const float*)d_in[13];
    const float* lng = (const float*)d_in[14];
    const float* lnb = (const float*)d_in[15];
    const float* nw1 = (const float*)d_in[16];
    const float* nb1 = (const float*)d_in[17];
    const float* nw2 = (const float*)d_in[18];
    const float* nb2 = (const float*)d_in[19];
    const float* rw1 = (const float*)d_in[20];
    const float* rb1 = (const float*)d_in[21];
    const float* rw2 = (const float*)d_in[22];
    const float* rb2 = (const float*)d_in[23];

    float* fA = (float*)d_ws;
    float* fB = fA + (size_t)Bq * Nn * DIMq;
    float* cA = fB + (size_t)Bq * Nn * DIMq;
    float* cB = cA + (size_t)Bq * Nn * 3;
    float* ew1T = cB + (size_t)Bq * Nn * 3;
    float* cw1T = ew1T + (size_t)DEPTHq * EH * WROW;

    {
        int tot = DEPTHq * EH * WROW + DEPTHq * CHID * MD;
        k_tw<<<(tot + 255) / 256, 256, 0, stream>>>(ew1, cw1, ew1T, cw1T);
    }
    k_init<<<(Bq * Nn * DIMq + 255) / 256, 256, 0, stream>>>(tokens, temb, pemb, fA);

    const float* fin = fA;
    const float* cin = coords;
    float* fbufs[2] = {fB, fA};
    float* cbufs[2] = {cA, cB};
    for (int l = 0; l < DEPTHq; ++l) {
        float* fout = fbufs[l & 1];
        float* cout = cbufs[l & 1];
        k_layer<<<Bq, 256, 0, stream>>>(fin, cin, fout, cout,
                                        ew1, eb1, ew1T, ew2, eb2,
                                        cw1T, cb1, cw2, cb2, csc,
                                        lng, lnb, nw1, nb1, nw2, nb2, l);
        fin = fout;
        cin = cout;
    }

    k_read<<<Bq, 64, 0, stream>>>(fin, rw1, rb1, rw2, rb2, (float*)d_out);
}

// Round 3
// 1042.698 us; speedup vs baseline: 3.5934x; 1.5507x over previous
//
#include <hip/hip_runtime.h>
#include <math.h>

#define Bq    1024
#define Nn    29
#define DIMq  64
#define Kq    8
#define MD    16
#define EIN   129
#define EH    258   // 2*EIN
#define CHID  64    // 4*MD
#define NIN   80    // DIM+MD
#define NHID  128   // 2*DIM
#define DEPTHq 4
#define PQS   261   // LDS row stride for P/Q (odd -> conflict-free j-gather)
#define FS    68    // s_f row stride (16B-aligned)

__device__ __forceinline__ float silu_f(float x) {
    float e = __expf(-x);
    return x * __builtin_amdgcn_rcpf(1.0f + e);
}

__global__ void k_init(const int* __restrict__ tokens,
                       const float* __restrict__ temb,
                       const float* __restrict__ pemb,
                       float* __restrict__ feats) {
    int o = blockIdx.x * 256 + threadIdx.x;
    if (o >= Bq * Nn * DIMq) return;
    int d = o & (DIMq - 1);
    int bn = o >> 6;
    int n = bn % Nn;
    int t = tokens[bn];
    feats[o] = temb[t * DIMq + d] + pemb[n * DIMq + d];
}

__global__ __launch_bounds__(256, 2)
void k_layer(const float* __restrict__ feats_in, const float* __restrict__ coors_in,
             float* __restrict__ feats_out, float* __restrict__ coors_out,
             const float* __restrict__ ew1, const float* __restrict__ eb1,
             const float* __restrict__ ew2, const float* __restrict__ eb2,
             const float* __restrict__ cw1, const float* __restrict__ cb1,
             const float* __restrict__ cw2, const float* __restrict__ cb2,
             const float* __restrict__ csc,
             const float* __restrict__ lng, const float* __restrict__ lnb,
             const float* __restrict__ nw1, const float* __restrict__ nb1,
             const float* __restrict__ nw2, const float* __restrict__ nb2,
             int layer) {
    ew1 += (size_t)layer * EIN * EH;   eb1 += layer * EH;
    ew2 += (size_t)layer * EH * MD;    eb2 += layer * MD;
    cw1 += (size_t)layer * MD * CHID;  cb1 += layer * CHID;
    cw2 += layer * CHID;               cb2 += layer;
    lng += layer * DIMq;               lnb += layer * DIMq;
    nw1 += (size_t)layer * NIN * NHID; nb1 += layer * NHID;
    nw2 += (size_t)layer * NHID * DIMq; nb2 += layer * DIMq;
    const float cscale = csc[layer];

    __shared__ float sPQ[2 * Nn * PQS];    // P rows [0..28], Q rows [29..57]; reused as ni/nh
    __shared__ float s_f[Nn][FS];
    __shared__ float s_c[Nn][3];
    __shared__ int   s_idx[Nn][Kq];
    __shared__ float s_dk[Nn][Kq];
    __shared__ float s_wd[EH];             // dist-row weights ew1[128][:]
    __shared__ float s_cw1T[CHID * MD];    // transposed coor W1
    __shared__ float s_cb1[CHID];
    __shared__ float s_cw2[CHID];
    __shared__ union RegB {                // d2 dead after kNN -> cw/mi
        float d2[Nn][Nn];
        struct { float cw[232]; float mi[Nn][MD]; } e;
    } ub;
    float* s_ni = sPQ;                     // [Nn][NIN]  (PQ dead after edge phase)
    float* s_nh = sPQ + Nn * NIN;          // [Nn][NHID]

    const int b = blockIdx.x;
    const int tid = threadIdx.x;

    // ---- stage: feats, coords, wd, coor-MLP weights ----
    const float* fb = feats_in + (size_t)b * Nn * DIMq;
    for (int o = tid; o < Nn * DIMq; o += 256) s_f[o >> 6][o & 63] = fb[o];
    for (int o = tid; o < Nn * 3; o += 256) s_c[0][o] = coors_in[(size_t)b * Nn * 3 + o];
    for (int o = tid; o < EH; o += 256) s_wd[o] = ew1[128 * EH + o];
    for (int o = tid; o < CHID * MD; o += 256) {
        int cc = o >> 4, i = o & 15;
        s_cw1T[o] = cw1[i * CHID + cc];
    }
    if (tid < CHID) { s_cb1[tid] = cb1[tid]; s_cw2[tid] = cw2[tid]; }
    __syncthreads();

    // ---- all-pairs squared distances (exact rounding: kNN-critical) ----
    for (int o = tid; o < Nn * Nn; o += 256) {
        int i = o / Nn, j = o % Nn;
        float dx = __fsub_rn(s_c[i][0], s_c[j][0]);
        float dy = __fsub_rn(s_c[i][1], s_c[j][1]);
        float dz = __fsub_rn(s_c[i][2], s_c[j][2]);
        ub.d2[i][j] = __fadd_rn(__fadd_rn(__fmul_rn(dx, dx), __fmul_rn(dy, dy)),
                                __fmul_rn(dz, dz));
    }
    __syncthreads();

    // ---- P/Q per-node matmuls: P[n][c] = eb1[c] + f_n . W1[0:64][c]
    //                            Q[n][c] =          f_n . W1[64:128][c]
    for (int c = tid; c < EH; c += 256) {
        float accP[Nn], accQ[Nn];
        float bias = eb1[c];
        #pragma unroll
        for (int n = 0; n < Nn; ++n) { accP[n] = bias; accQ[n] = 0.f; }
        const float* w1c = ew1 + c;
        #pragma unroll 2
        for (int ig = 0; ig < 16; ++ig) {
            float wp0 = w1c[(4 * ig + 0) * EH], wp1 = w1c[(4 * ig + 1) * EH];
            float wp2 = w1c[(4 * ig + 2) * EH], wp3 = w1c[(4 * ig + 3) * EH];
            float wq0 = w1c[(64 + 4 * ig + 0) * EH], wq1 = w1c[(64 + 4 * ig + 1) * EH];
            float wq2 = w1c[(64 + 4 * ig + 2) * EH], wq3 = w1c[(64 + 4 * ig + 3) * EH];
            #pragma unroll
            for (int n = 0; n < Nn; ++n) {
                float4 f4 = *(const float4*)&s_f[n][4 * ig];
                accP[n] = fmaf(f4.x, wp0, accP[n]);
                accP[n] = fmaf(f4.y, wp1, accP[n]);
                accP[n] = fmaf(f4.z, wp2, accP[n]);
                accP[n] = fmaf(f4.w, wp3, accP[n]);
                accQ[n] = fmaf(f4.x, wq0, accQ[n]);
                accQ[n] = fmaf(f4.y, wq1, accQ[n]);
                accQ[n] = fmaf(f4.z, wq2, accQ[n]);
                accQ[n] = fmaf(f4.w, wq3, accQ[n]);
            }
        }
        #pragma unroll
        for (int n = 0; n < Nn; ++n) {
            sPQ[n * PQS + c] = accP[n];
            sPQ[(Nn + n) * PQS + c] = accQ[n];
        }
    }

    // ---- stable K-nearest (matches top_k(-d2) tie semantics) ----
    if (tid < Nn) {
        unsigned chosen = 0;
        for (int r = 0; r < Kq; ++r) {
            float best = 3.4e38f; int bj = 0;
            for (int j = 0; j < Nn; ++j) {
                if ((chosen >> j) & 1u) continue;
                float v = ub.d2[tid][j];
                if (v < best) { best = v; bj = j; }
            }
            chosen |= 1u << bj;
            s_idx[tid][r] = bj;
            s_dk[tid][r] = best;
        }
    }
    __syncthreads();

    // ---- per-edge: h=silu(P[i]+Q[j]+d*wd) streamed into m accumulation ----
    if (tid < Nn * Kq) {
        const int e = tid, n = e >> 3, k = e & 7;
        const int jj = s_idx[n][k];
        const float dd = s_dk[n][k];
        const float* Prow = sPQ + n * PQS;
        const float* Qrow = sPQ + (Nn + jj) * PQS;

        float m[MD];
        #pragma unroll
        for (int q = 0; q < MD; ++q) m[q] = 0.f;

        #pragma unroll 2
        for (int c = 0; c < EH; ++c) {
            float pre = Prow[c] + Qrow[c] + dd * s_wd[c];
            float h = silu_f(pre);
            const float4* w2 = (const float4*)(ew2 + (size_t)c * MD);
            float4 a0 = w2[0], a1 = w2[1], a2 = w2[2], a3 = w2[3];
            m[0]  = fmaf(h, a0.x, m[0]);  m[1]  = fmaf(h, a0.y, m[1]);
            m[2]  = fmaf(h, a0.z, m[2]);  m[3]  = fmaf(h, a0.w, m[3]);
            m[4]  = fmaf(h, a1.x, m[4]);  m[5]  = fmaf(h, a1.y, m[5]);
            m[6]  = fmaf(h, a1.z, m[6]);  m[7]  = fmaf(h, a1.w, m[7]);
            m[8]  = fmaf(h, a2.x, m[8]);  m[9]  = fmaf(h, a2.y, m[9]);
            m[10] = fmaf(h, a2.z, m[10]); m[11] = fmaf(h, a2.w, m[11]);
            m[12] = fmaf(h, a3.x, m[12]); m[13] = fmaf(h, a3.y, m[13]);
            m[14] = fmaf(h, a3.z, m[14]); m[15] = fmaf(h, a3.w, m[15]);
        }
        #pragma unroll
        for (int q = 0; q < MD; ++q) m[q] = silu_f(eb2[q] + m[q]);

        // coor MLP per edge (weights from LDS)
        float cwacc = cb2[0];
        for (int cc = 0; cc < CHID; ++cc) {
            const float4* wr = (const float4*)(s_cw1T + cc * MD);
            float4 w0 = wr[0], w1 = wr[1], w2v = wr[2], w3 = wr[3];
            float hh = s_cb1[cc];
            hh = fmaf(m[0],  w0.x, hh);  hh = fmaf(m[1],  w0.y, hh);
            hh = fmaf(m[2],  w0.z, hh);  hh = fmaf(m[3],  w0.w, hh);
            hh = fmaf(m[4],  w1.x, hh);  hh = fmaf(m[5],  w1.y, hh);
            hh = fmaf(m[6],  w1.z, hh);  hh = fmaf(m[7],  w1.w, hh);
            hh = fmaf(m[8],  w2v.x, hh); hh = fmaf(m[9],  w2v.y, hh);
            hh = fmaf(m[10], w2v.z, hh); hh = fmaf(m[11], w2v.w, hh);
            hh = fmaf(m[12], w3.x, hh);  hh = fmaf(m[13], w3.y, hh);
            hh = fmaf(m[14], w3.z, hh);  hh = fmaf(m[15], w3.w, hh);
            hh = silu_f(hh);
            cwacc = fmaf(hh, s_cw2[cc], cwacc);
        }
        cwacc = fminf(fmaxf(cwacc, -2.f), 2.f);
        ub.e.cw[e] = cwacc;

        // m_i pool over the node's 8 consecutive lanes
        #pragma unroll
        for (int q = 0; q < MD; ++q) {
            float v = m[q];
            v += __shfl_xor(v, 1);
            v += __shfl_xor(v, 2);
            v += __shfl_xor(v, 4);
            if (k == 0) ub.e.mi[n][q] = v;
        }
    }
    __syncthreads();

    // ---- coords update + LayerNorm/node-input build (PQ region becomes ni/nh) ----
    if (tid < Nn * 3) {
        int n2 = tid / 3, cix = tid % 3;
        float acc = 0.f;
        for (int k2 = 0; k2 < Kq; ++k2) {
            int j2 = s_idx[n2][k2];
            float nrm = sqrtf(s_dk[n2][k2]);
            float rel = __fsub_rn(s_c[n2][cix], s_c[j2][cix]);
            float rn = rel / fmaxf(nrm, 1e-8f) * cscale;
            acc = fmaf(ub.e.cw[n2 * Kq + k2], rn, acc);
        }
        coors_out[((size_t)b * Nn + n2) * 3 + cix] = s_c[n2][cix] + acc;
    }
    if (tid < Nn) {
        float mu = 0.f;
        for (int d = 0; d < DIMq; ++d) mu += s_f[tid][d];
        mu *= (1.0f / 64.0f);
        float var = 0.f;
        for (int d = 0; d < DIMq; ++d) { float t = s_f[tid][d] - mu; var = fmaf(t, t, var); }
        var *= (1.0f / 64.0f);
        float rs = rsqrtf(var + 1e-5f);
        for (int d = 0; d < DIMq; ++d)
            s_ni[tid * NIN + d] = (s_f[tid][d] - mu) * rs * lng[d] + lnb[d];
        for (int c2 = 0; c2 < MD; ++c2) s_ni[tid * NIN + DIMq + c2] = ub.e.mi[tid][c2];
    }
    __syncthreads();

    // ---- node MLP hidden (float4 broadcast reads of ni) ----
    for (int o = tid; o < Nn * NHID; o += 256) {
        int n2 = o >> 7, c = o & 127;
        float acc = nb1[c];
        const float* nir = s_ni + n2 * NIN;
        const float* w = nw1 + c;
        #pragma unroll 4
        for (int ig = 0; ig < 20; ++ig) {
            float4 f4 = *(const float4*)(nir + 4 * ig);
            acc = fmaf(f4.x, w[(4 * ig + 0) * NHID], acc);
            acc = fmaf(f4.y, w[(4 * ig + 1) * NHID], acc);
            acc = fmaf(f4.z, w[(4 * ig + 2) * NHID], acc);
            acc = fmaf(f4.w, w[(4 * ig + 3) * NHID], acc);
        }
        s_nh[n2 * NHID + c] = silu_f(acc);
    }
    __syncthreads();

    // ---- node MLP out + residual ----
    for (int o = tid; o < Nn * DIMq; o += 256) {
        int n2 = o >> 6, c = o & 63;
        float acc = nb2[c];
        const float* nhr = s_nh + n2 * NHID;
        const float* w = nw2 + c;
        #pragma unroll 4
        for (int ig = 0; ig < 32; ++ig) {
            float4 f4 = *(const float4*)(nhr + 4 * ig);
            acc = fmaf(f4.x, w[(4 * ig + 0) * DIMq], acc);
            acc = fmaf(f4.y, w[(4 * ig + 1) * DIMq], acc);
            acc = fmaf(f4.z, w[(4 * ig + 2) * DIMq], acc);
            acc = fmaf(f4.w, w[(4 * ig + 3) * DIMq], acc);
        }
        feats_out[((size_t)b * Nn + n2) * DIMq + c] = acc + s_f[n2][c];
    }
}

__global__ __launch_bounds__(64)
void k_read(const float* __restrict__ feats,
            const float* __restrict__ rw1, const float* __restrict__ rb1,
            const float* __restrict__ rw2, const float* __restrict__ rb2,
            float* __restrict__ out) {
    __shared__ float s_mol[DIMq];
    const int b = blockIdx.x, t = threadIdx.x;
    float acc = 0.f;
    for (int n = 0; n < Nn; ++n) acc += feats[((size_t)b * Nn + n) * DIMq + t];
    s_mol[t] = acc / 29.0f;
    __syncthreads();
    float a2 = rb1[t];
    for (int i = 0; i < DIMq; ++i) a2 = fmaf(s_mol[i], rw1[i * DIMq + t], a2);
    float part = silu_f(a2) * rw2[t];
    #pragma unroll
    for (int off = 32; off > 0; off >>= 1) part += __shfl_down(part, off);
    if (t == 0) out[b] = part + rb2[0];
}

extern "C" void kernel_launch(void* const* d_in, const int* in_sizes, int n_in,
                              void* d_out, int out_size, void* d_ws, size_t ws_size,
                              hipStream_t stream) {
    const int*   tokens = (const int*)d_in[0];
    const float* coords = (const float*)d_in[1];
    // d_in[2] = mask : all-True in this problem
    const float* temb = (const float*)d_in[3];
    const float* pemb = (const float*)d_in[4];
    const float* ew1 = (const float*)d_in[5];
    const float* eb1 = (const float*)d_in[6];
    const float* ew2 = (const float*)d_in[7];
    const float* eb2 = (const float*)d_in[8];
    const float* cw1 = (const float*)d_in[9];
    const float* cb1 = (const float*)d_in[10];
    const float* cw2 = (const float*)d_in[11];
    const float* cb2 = (const float*)d_in[12];
    const float* csc = (const float*)d_in[13];
    const float* lng = (const float*)d_in[14];
    const float* lnb = (const float*)d_in[15];
    const float* nw1 = (const float*)d_in[16];
    const float* nb1 = (const float*)d_in[17];
    const float* nw2 = (const float*)d_in[18];
    const float* nb2 = (const float*)d_in[19];
    const float* rw1 = (const float*)d_in[20];
    const float* rb1 = (const float*)d_in[21];
    const float* rw2 = (const float*)d_in[22];
    const float* rb2 = (const float*)d_in[23];

    float* fA = (float*)d_ws;
    float* fB = fA + (size_t)Bq * Nn * DIMq;
    float* cA = fB + (size_t)Bq * Nn * DIMq;
    float* cB = cA + (size_t)Bq * Nn * 3;

    k_init<<<(Bq * Nn * DIMq + 255) / 256, 256, 0, stream>>>(tokens, temb, pemb, fA);

    const float* fin = fA;
    const float* cin = coords;
    float* fbufs[2] = {fB, fA};
    float* cbufs[2] = {cA, cB};
    for (int l = 0; l < DEPTHq; ++l) {
        float* fout = fbufs[l & 1];
        float* cout = cbufs[l & 1];
        k_layer<<<Bq, 256, 0, stream>>>(fin, cin, fout, cout,
                                        ew1, eb1, ew2, eb2,
                                        cw1, cb1, cw2, cb2, csc,
                                        lng, lnb, nw1, nb1, nw2, nb2, l);
        fin = fout;
        cin = cout;
    }

    k_read<<<Bq, 64, 0, stream>>>(fin, rw1, rb1, rw2, rb2, (float*)d_out);
}

// Round 4
// 940.123 us; speedup vs baseline: 3.9855x; 1.1091x over previous
//
#include <hip/hip_runtime.h>
#include <math.h>

#define Bq    1024
#define Nn    29
#define DIMq  64
#define Kq    8
#define MD    16
#define EIN   129
#define EH    258   // 2*EIN
#define CHID  64    // 4*MD
#define NIN   80    // DIM+MD
#define NHID  128   // 2*DIM
#define DEPTHq 4
#define PQS2  132   // P/Q LDS row stride (16B aligned, conflict-tiled)
#define FS    68    // s_f row stride

__device__ __forceinline__ float silu_f(float x) {
    float e = __expf(-x);
    return x * __builtin_amdgcn_rcpf(1.0f + e);
}

__global__ void k_init(const int* __restrict__ tokens,
                       const float* __restrict__ temb,
                       const float* __restrict__ pemb,
                       float* __restrict__ feats) {
    int o = blockIdx.x * 256 + threadIdx.x;
    if (o >= Bq * Nn * DIMq) return;
    int d = o & (DIMq - 1);
    int bn = o >> 6;
    int n = bn % Nn;
    int t = tokens[bn];
    feats[o] = temb[t * DIMq + d] + pemb[n * DIMq + d];
}

__global__ __launch_bounds__(256, 3)
void k_layer(const float* __restrict__ feats_in, const float* __restrict__ coors_in,
             float* __restrict__ feats_out, float* __restrict__ coors_out,
             const float* __restrict__ ew1, const float* __restrict__ eb1,
             const float* __restrict__ ew2, const float* __restrict__ eb2,
             const float* __restrict__ cw1, const float* __restrict__ cb1,
             const float* __restrict__ cw2, const float* __restrict__ cb2,
             const float* __restrict__ csc,
             const float* __restrict__ lng, const float* __restrict__ lnb,
             const float* __restrict__ nw1, const float* __restrict__ nb1,
             const float* __restrict__ nw2, const float* __restrict__ nb2,
             int layer) {
    ew1 += (size_t)layer * EIN * EH;   eb1 += layer * EH;
    ew2 += (size_t)layer * EH * MD;    eb2 += layer * MD;
    cw1 += (size_t)layer * MD * CHID;  cb1 += layer * CHID;
    cw2 += layer * CHID;               cb2 += layer;
    lng += layer * DIMq;               lnb += layer * DIMq;
    nw1 += (size_t)layer * NIN * NHID; nb1 += layer * NHID;
    nw2 += (size_t)layer * NHID * DIMq; nb2 += layer * DIMq;
    const float cscale = csc[layer];

    __shared__ float sPQ[2 * Nn * PQS2];   // P rows [0..28], Q rows [29..57] (c-half); later ni/nh
    __shared__ float s_f[Nn][FS];
    __shared__ float s_c[Nn][3];
    __shared__ int   s_idx[Nn][Kq];
    __shared__ float s_dk[Nn][Kq];
    __shared__ union RegB {                // d2 dead after kNN -> cw/mi
        float d2[Nn][Nn];
        struct { float cw[232]; float mi[Nn][MD]; } e;
    } ub;
    float* s_ni = sPQ;                     // [Nn][NIN]  (PQ dead after edge phase)
    float* s_nh = sPQ + Nn * NIN;          // [Nn][NHID]

    const int b = blockIdx.x;
    const int tid = threadIdx.x;

    // ---- stage feats + coords ----
    const float* fb = feats_in + (size_t)b * Nn * DIMq;
    for (int o = tid; o < Nn * DIMq; o += 256) s_f[o >> 6][o & 63] = fb[o];
    for (int o = tid; o < Nn * 3; o += 256) s_c[0][o] = coors_in[(size_t)b * Nn * 3 + o];
    __syncthreads();

    // ---- all-pairs squared distances (exact rounding: kNN-critical) ----
    for (int o = tid; o < Nn * Nn; o += 256) {
        int i = o / Nn, j = o % Nn;
        float dx = __fsub_rn(s_c[i][0], s_c[j][0]);
        float dy = __fsub_rn(s_c[i][1], s_c[j][1]);
        float dz = __fsub_rn(s_c[i][2], s_c[j][2]);
        ub.d2[i][j] = __fadd_rn(__fadd_rn(__fmul_rn(dx, dx), __fmul_rn(dy, dy)),
                                __fmul_rn(dz, dz));
    }
    __syncthreads();

    // ---- stable K-nearest (matches top_k(-d2) tie semantics) ----
    if (tid < Nn) {
        unsigned chosen = 0;
        for (int r = 0; r < Kq; ++r) {
            float best = 3.4e38f; int bj = 0;
            for (int j = 0; j < Nn; ++j) {
                if ((chosen >> j) & 1u) continue;
                float v = ub.d2[tid][j];
                if (v < best) { best = v; bj = j; }
            }
            chosen |= 1u << bj;
            s_idx[tid][r] = bj;
            s_dk[tid][r] = best;
        }
    }
    __syncthreads();

    // ---- edge state (uniform flow: all 256 lanes run; writes masked) ----
    const int e   = (tid < 232) ? tid : 231;
    const int n_e = e >> 3;
    const int k_e = e & 7;
    const int jj  = s_idx[n_e][k_e];
    const float dd = s_dk[n_e][k_e];
    float m[MD];
    #pragma unroll
    for (int q = 0; q < MD; ++q) m[q] = 0.f;

    // ---- two c-halves: P/Q panel compute -> per-edge streamed accumulation ----
    for (int pass = 0; pass < 2; ++pass) {
        const int c0 = pass * 128;
        const int NC = pass ? 130 : 128;

        // P/Q: task t<NC -> P col c0+t ; else Q col c0+(t-NC)
        for (int t = tid; t < 2 * NC; t += 256) {
            const bool isP = t < NC;
            const int cl = isP ? t : t - NC;
            const int cg = c0 + cl;
            const float* wcol = ew1 + (isP ? 0 : 64) * EH + cg;
            float init = isP ? eb1[cg] : 0.f;
            float acc[Nn];
            #pragma unroll
            for (int n = 0; n < Nn; ++n) acc[n] = init;
            #pragma unroll 2
            for (int ig = 0; ig < 16; ++ig) {
                float w0 = wcol[(4 * ig + 0) * EH], w1 = wcol[(4 * ig + 1) * EH];
                float w2v = wcol[(4 * ig + 2) * EH], w3 = wcol[(4 * ig + 3) * EH];
                #pragma unroll
                for (int n = 0; n < Nn; ++n) {
                    float4 f4 = *(const float4*)&s_f[n][4 * ig];
                    acc[n] = fmaf(f4.x, w0, acc[n]);
                    acc[n] = fmaf(f4.y, w1, acc[n]);
                    acc[n] = fmaf(f4.z, w2v, acc[n]);
                    acc[n] = fmaf(f4.w, w3, acc[n]);
                }
            }
            const int rbase = isP ? 0 : Nn;
            #pragma unroll
            for (int n = 0; n < Nn; ++n) sPQ[(rbase + n) * PQS2 + cl] = acc[n];
        }
        __syncthreads();

        // edge accumulation over this c-half (uniform loop; scalar weight reads)
        {
            const float* Prow = sPQ + n_e * PQS2;
            const float* Qrow = sPQ + (Nn + jj) * PQS2;
            const float* wdrow = ew1 + 128 * EH;
            for (int cl = 0; cl < 128; cl += 4) {
                float4 P4 = *(const float4*)(Prow + cl);
                float4 Q4 = *(const float4*)(Qrow + cl);
                #pragma unroll
                for (int u = 0; u < 4; ++u) {
                    const int cg = c0 + cl + u;
                    float Pv = (&P4.x)[u];
                    float Qv = (&Q4.x)[u];
                    float pre = Pv + Qv + dd * wdrow[cg];
                    float h = silu_f(pre);
                    const float* w2 = ew2 + (size_t)cg * MD;
                    #pragma unroll
                    for (int q = 0; q < MD; ++q) m[q] = fmaf(h, w2[q], m[q]);
                }
            }
            if (pass) {
                #pragma unroll
                for (int cl = 128; cl < 130; ++cl) {
                    const int cg = c0 + cl;
                    float pre = Prow[cl] + Qrow[cl] + dd * wdrow[cg];
                    float h = silu_f(pre);
                    const float* w2 = ew2 + (size_t)cg * MD;
                    #pragma unroll
                    for (int q = 0; q < MD; ++q) m[q] = fmaf(h, w2[q], m[q]);
                }
            }
        }
        __syncthreads();
    }

    // ---- finish edge: m silu, coor MLP, cw + mi pool ----
    {
        #pragma unroll
        for (int q = 0; q < MD; ++q) m[q] = silu_f(eb2[q] + m[q]);

        float cwacc = cb2[0];
        #pragma unroll
        for (int ch = 0; ch < 4; ++ch) {         // cc = 16*ch .. 16*ch+15
            float hh[16];
            const float* cb1c = cb1 + 16 * ch;
            #pragma unroll
            for (int q = 0; q < 16; ++q) hh[q] = cb1c[q];
            #pragma unroll
            for (int i = 0; i < MD; ++i) {
                const float* wr = cw1 + i * CHID + 16 * ch;   // contiguous 16 floats, uniform
                #pragma unroll
                for (int q = 0; q < 16; ++q) hh[q] = fmaf(m[i], wr[q], hh[q]);
            }
            const float* cw2c = cw2 + 16 * ch;
            #pragma unroll
            for (int q = 0; q < 16; ++q) cwacc = fmaf(silu_f(hh[q]), cw2c[q], cwacc);
        }
        cwacc = fminf(fmaxf(cwacc, -2.f), 2.f);
        if (tid < 232) ub.e.cw[e] = cwacc;

        #pragma unroll
        for (int q = 0; q < MD; ++q) {
            float v = m[q];
            v += __shfl_xor(v, 1);
            v += __shfl_xor(v, 2);
            v += __shfl_xor(v, 4);
            if (k_e == 0 && tid < 232) ub.e.mi[n_e][q] = v;
        }
    }
    __syncthreads();

    // ---- coords update + LayerNorm/node-input build (PQ region becomes ni/nh) ----
    if (tid < Nn * 3) {
        int n2 = tid / 3, cix = tid % 3;
        float acc = 0.f;
        for (int k2 = 0; k2 < Kq; ++k2) {
            int j2 = s_idx[n2][k2];
            float nrm = sqrtf(s_dk[n2][k2]);
            float rel = __fsub_rn(s_c[n2][cix], s_c[j2][cix]);
            float rn = rel / fmaxf(nrm, 1e-8f) * cscale;
            acc = fmaf(ub.e.cw[n2 * Kq + k2], rn, acc);
        }
        coors_out[((size_t)b * Nn + n2) * 3 + cix] = s_c[n2][cix] + acc;
    }
    if (tid < Nn) {
        float mu = 0.f;
        for (int d = 0; d < DIMq; ++d) mu += s_f[tid][d];
        mu *= (1.0f / 64.0f);
        float var = 0.f;
        for (int d = 0; d < DIMq; ++d) { float t = s_f[tid][d] - mu; var = fmaf(t, t, var); }
        var *= (1.0f / 64.0f);
        float rs = rsqrtf(var + 1e-5f);
        for (int d = 0; d < DIMq; ++d)
            s_ni[tid * NIN + d] = (s_f[tid][d] - mu) * rs * lng[d] + lnb[d];
        for (int c2 = 0; c2 < MD; ++c2) s_ni[tid * NIN + DIMq + c2] = ub.e.mi[tid][c2];
    }
    __syncthreads();

    // ---- node MLP hidden ----
    for (int o = tid; o < Nn * NHID; o += 256) {
        int n2 = o >> 7, c = o & 127;
        float acc = nb1[c];
        const float* nir = s_ni + n2 * NIN;
        const float* w = nw1 + c;
        #pragma unroll 4
        for (int ig = 0; ig < 20; ++ig) {
            float4 f4 = *(const float4*)(nir + 4 * ig);
            acc = fmaf(f4.x, w[(4 * ig + 0) * NHID], acc);
            acc = fmaf(f4.y, w[(4 * ig + 1) * NHID], acc);
            acc = fmaf(f4.z, w[(4 * ig + 2) * NHID], acc);
            acc = fmaf(f4.w, w[(4 * ig + 3) * NHID], acc);
        }
        s_nh[n2 * NHID + c] = silu_f(acc);
    }
    __syncthreads();

    // ---- node MLP out + residual ----
    for (int o = tid; o < Nn * DIMq; o += 256) {
        int n2 = o >> 6, c = o & 63;
        float acc = nb2[c];
        const float* nhr = s_nh + n2 * NHID;
        const float* w = nw2 + c;
        #pragma unroll 4
        for (int ig = 0; ig < 32; ++ig) {
            float4 f4 = *(const float4*)(nhr + 4 * ig);
            acc = fmaf(f4.x, w[(4 * ig + 0) * DIMq], acc);
            acc = fmaf(f4.y, w[(4 * ig + 1) * DIMq], acc);
            acc = fmaf(f4.z, w[(4 * ig + 2) * DIMq], acc);
            acc = fmaf(f4.w, w[(4 * ig + 3) * DIMq], acc);
        }
        feats_out[((size_t)b * Nn + n2) * DIMq + c] = acc + s_f[n2][c];
    }
}

__global__ __launch_bounds__(64)
void k_read(const float* __restrict__ feats,
            const float* __restrict__ rw1, const float* __restrict__ rb1,
            const float* __restrict__ rw2, const float* __restrict__ rb2,
             float* __restrict__ out) {
    __shared__ float s_mol[DIMq];
    const int b = blockIdx.x, t = threadIdx.x;
    float acc = 0.f;
    for (int n = 0; n < Nn; ++n) acc += feats[((size_t)b * Nn + n) * DIMq + t];
    s_mol[t] = acc / 29.0f;
    __syncthreads();
    float a2 = rb1[t];
    for (int i = 0; i < DIMq; ++i) a2 = fmaf(s_mol[i], rw1[i * DIMq + t], a2);
    float part = silu_f(a2) * rw2[t];
    #pragma unroll
    for (int off = 32; off > 0; off >>= 1) part += __shfl_down(part, off);
    if (t == 0) out[b] = part + rb2[0];
}

extern "C" void kernel_launch(void* const* d_in, const int* in_sizes, int n_in,
                              void* d_out, int out_size, void* d_ws, size_t ws_size,
                              hipStream_t stream) {
    const int*   tokens = (const int*)d_in[0];
    const float* coords = (const float*)d_in[1];
    // d_in[2] = mask : all-True in this problem
    const float* temb = (const float*)d_in[3];
    const float* pemb = (const float*)d_in[4];
    const float* ew1 = (const float*)d_in[5];
    const float* eb1 = (const float*)d_in[6];
    const float* ew2 = (const float*)d_in[7];
    const float* eb2 = (const float*)d_in[8];
    const float* cw1 = (const float*)d_in[9];
    const float* cb1 = (const float*)d_in[10];
    const float* cw2 = (const float*)d_in[11];
    const float* cb2 = (const float*)d_in[12];
    const float* csc = (const float*)d_in[13];
    const float* lng = (const float*)d_in[14];
    const float* lnb = (const float*)d_in[15];
    const float* nw1 = (const float*)d_in[16];
    const float* nb1 = (const float*)d_in[17];
    const float* nw2 = (const float*)d_in[18];
    const float* nb2 = (const float*)d_in[19];
    const float* rw1 = (const float*)d_in[20];
    const float* rb1 = (const float*)d_in[21];
    const float* rw2 = (const float*)d_in[22];
    const float* rb2 = (const float*)d_in[23];

    float* fA = (float*)d_ws;
    float* fB = fA + (size_t)Bq * Nn * DIMq;
    float* cA = fB + (size_t)Bq * Nn * DIMq;
    float* cB = cA + (size_t)Bq * Nn * 3;

    k_init<<<(Bq * Nn * DIMq + 255) / 256, 256, 0, stream>>>(tokens, temb, pemb, fA);

    const float* fin = fA;
    const float* cin = coords;
    float* fbufs[2] = {fB, fA};
    float* cbufs[2] = {cA, cB};
    for (int l = 0; l < DEPTHq; ++l) {
        float* fout = fbufs[l & 1];
        float* cout = cbufs[l & 1];
        k_layer<<<Bq, 256, 0, stream>>>(fin, cin, fout, cout,
                                        ew1, eb1, ew2, eb2,
                                        cw1, cb1, cw2, cb2, csc,
                                        lng, lnb, nw1, nb1, nw2, nb2, l);
        fin = fout;
        cin = cout;
    }

    k_read<<<Bq, 64, 0, stream>>>(fin, rw1, rb1, rw2, rb2, (float*)d_out);
}

// Round 5
// 632.866 us; speedup vs baseline: 5.9204x; 1.4855x over previous
//
#include <hip/hip_runtime.h>
#include <math.h>

#define Bq    1024
#define Nn    29
#define DIMq  64
#define Kq    8
#define MD    16
#define EIN   129
#define EH    258   // 2*EIN
#define CHID  64    // 4*MD
#define NIN   80    // DIM+MD
#define NHID  128   // 2*DIM
#define DEPTHq 4
#define NPASS 3
#define PCOLS 86    // columns per c-pass (3*86 = 258)
#define PQS3  92    // P/Q LDS row stride (4*23: 16B-aligned, odd quad -> bank spread)
#define FS    68    // s_f row stride
#define UPQN  6032  // union size: max(2*29*92=5336, ni 2320 + nh 3712 = 6032)

__device__ __forceinline__ float silu_f(float x) {
    float e = __expf(-x);
    return x * __builtin_amdgcn_rcpf(1.0f + e);
}

__global__ void k_init(const int* __restrict__ tokens,
                       const float* __restrict__ temb,
                       const float* __restrict__ pemb,
                       float* __restrict__ feats) {
    int o = blockIdx.x * 256 + threadIdx.x;
    if (o >= Bq * Nn * DIMq) return;
    int d = o & (DIMq - 1);
    int bn = o >> 6;
    int n = bn % Nn;
    int t = tokens[bn];
    feats[o] = temb[t * DIMq + d] + pemb[n * DIMq + d];
}

__global__ __launch_bounds__(256, 4)
void k_layer(const float* __restrict__ feats_in, const float* __restrict__ coors_in,
             float* __restrict__ feats_out, float* __restrict__ coors_out,
             const float* __restrict__ ew1, const float* __restrict__ eb1,
             const float* __restrict__ ew2, const float* __restrict__ eb2,
             const float* __restrict__ cw1, const float* __restrict__ cb1,
             const float* __restrict__ cw2, const float* __restrict__ cb2,
             const float* __restrict__ csc,
             const float* __restrict__ lng, const float* __restrict__ lnb,
             const float* __restrict__ nw1, const float* __restrict__ nb1,
             const float* __restrict__ nw2, const float* __restrict__ nb2,
             int layer) {
    ew1 += (size_t)layer * EIN * EH;   eb1 += layer * EH;
    ew2 += (size_t)layer * EH * MD;    eb2 += layer * MD;
    cw1 += (size_t)layer * MD * CHID;  cb1 += layer * CHID;
    cw2 += layer * CHID;               cb2 += layer;
    lng += layer * DIMq;               lnb += layer * DIMq;
    nw1 += (size_t)layer * NIN * NHID; nb1 += layer * NHID;
    nw2 += (size_t)layer * NHID * DIMq; nb2 += layer * DIMq;
    const float cscale = csc[layer];

    __shared__ float uPQ[UPQN];            // P rows [0..28], Q rows [29..57] per c-pass; later ni/nh
    __shared__ float s_f[Nn][FS];
    __shared__ float s_c[Nn][3];
    __shared__ int   s_idx[Nn][Kq];
    __shared__ float s_dk[Nn][Kq];
    __shared__ union RegB {                // d2 dead after kNN -> cw/mi
        float d2[Nn][Nn];
        struct { float cw[232]; float mi[Nn][MD]; } e;
    } ub;
    float* s_ni = uPQ;                     // [Nn][NIN]
    float* s_nh = uPQ + Nn * NIN;          // [Nn][NHID]

    const int b = blockIdx.x;
    const int tid = threadIdx.x;

    // ---- stage feats + coords ----
    const float* fb = feats_in + (size_t)b * Nn * DIMq;
    for (int o = tid; o < Nn * DIMq; o += 256) s_f[o >> 6][o & 63] = fb[o];
    for (int o = tid; o < Nn * 3; o += 256) s_c[0][o] = coors_in[(size_t)b * Nn * 3 + o];
    __syncthreads();

    // ---- all-pairs squared distances (exact rounding: kNN-critical) ----
    for (int o = tid; o < Nn * Nn; o += 256) {
        int i = o / Nn, j = o % Nn;
        float dx = __fsub_rn(s_c[i][0], s_c[j][0]);
        float dy = __fsub_rn(s_c[i][1], s_c[j][1]);
        float dz = __fsub_rn(s_c[i][2], s_c[j][2]);
        ub.d2[i][j] = __fadd_rn(__fadd_rn(__fmul_rn(dx, dx), __fmul_rn(dy, dy)),
                                __fmul_rn(dz, dz));
    }
    __syncthreads();

    // ---- parallel stable K-nearest: 8 lanes per node, shfl min-reduce ----
    // tie rule (smaller dist2, then smaller j) == jax.lax.top_k(-d2) order
    if (tid < Nn * Kq) {
        const int g = tid >> 3, l = tid & 7;
        unsigned chosen = 0;
        for (int r = 0; r < Kq; ++r) {
            float bv = 3.4e38f; int bj = 64;
            for (int j = l; j < Nn; j += 8) {
                if ((chosen >> j) & 1u) continue;
                float v = ub.d2[g][j];
                if (v < bv) { bv = v; bj = j; }
            }
            #pragma unroll
            for (int off = 1; off < 8; off <<= 1) {
                float ov = __shfl_xor(bv, off);
                int   oj = __shfl_xor(bj, off);
                if (ov < bv || (ov == bv && oj < bj)) { bv = ov; bj = oj; }
            }
            chosen |= 1u << bj;
            if (l == 0) { s_idx[g][r] = bj; s_dk[g][r] = bv; }
        }
    }
    __syncthreads();

    // ---- edge state (uniform flow: all 256 lanes run; writes masked) ----
    const int e   = (tid < 232) ? tid : 231;
    const int n_e = e >> 3;
    const int k_e = e & 7;
    const int jj  = s_idx[n_e][k_e];
    const float dd = s_dk[n_e][k_e];
    float m[MD];
    #pragma unroll
    for (int q = 0; q < MD; ++q) m[q] = 0.f;

    // ---- three c-passes: P/Q panel compute -> per-edge streamed accumulation ----
    for (int pass = 0; pass < NPASS; ++pass) {
        const int c0 = pass * PCOLS;

        // P/Q: task t<PCOLS -> P col, else Q col (172 tasks, one strided iter)
        if (tid < 2 * PCOLS) {
            const int t = tid;
            const bool isP = t < PCOLS;
            const int cl = isP ? t : t - PCOLS;
            const int cg = c0 + cl;
            const float* wcol = ew1 + (isP ? 0 : 64) * EH + cg;
            float init = isP ? eb1[cg] : 0.f;
            float acc[Nn];
            #pragma unroll
            for (int n = 0; n < Nn; ++n) acc[n] = init;
            #pragma unroll 2
            for (int ig = 0; ig < 16; ++ig) {
                float w0 = wcol[(4 * ig + 0) * EH], w1 = wcol[(4 * ig + 1) * EH];
                float w2v = wcol[(4 * ig + 2) * EH], w3 = wcol[(4 * ig + 3) * EH];
                #pragma unroll
                for (int n = 0; n < Nn; ++n) {
                    float4 f4 = *(const float4*)&s_f[n][4 * ig];
                    acc[n] = fmaf(f4.x, w0, acc[n]);
                    acc[n] = fmaf(f4.y, w1, acc[n]);
                    acc[n] = fmaf(f4.z, w2v, acc[n]);
                    acc[n] = fmaf(f4.w, w3, acc[n]);
                }
            }
            const int rbase = isP ? 0 : Nn;
            #pragma unroll
            for (int n = 0; n < Nn; ++n) uPQ[(rbase + n) * PQS3 + cl] = acc[n];
        }
        __syncthreads();

        // edge accumulation over this c-pass (uniform loop; scalar weight reads)
        {
            const float* Prow = uPQ + n_e * PQS3;
            const float* Qrow = uPQ + (Nn + jj) * PQS3;
            const float* wdrow = ew1 + 128 * EH;
            for (int cl = 0; cl < 84; cl += 4) {
                float4 P4 = *(const float4*)(Prow + cl);
                float4 Q4 = *(const float4*)(Qrow + cl);
                #pragma unroll
                for (int u = 0; u < 4; ++u) {
                    const int cg = c0 + cl + u;
                    float pre = (&P4.x)[u] + (&Q4.x)[u] + dd * wdrow[cg];
                    float h = silu_f(pre);
                    const float* w2 = ew2 + (size_t)cg * MD;
                    #pragma unroll
                    for (int q = 0; q < MD; ++q) m[q] = fmaf(h, w2[q], m[q]);
                }
            }
            #pragma unroll
            for (int cl = 84; cl < PCOLS; ++cl) {
                const int cg = c0 + cl;
                float pre = Prow[cl] + Qrow[cl] + dd * wdrow[cg];
                float h = silu_f(pre);
                const float* w2 = ew2 + (size_t)cg * MD;
                #pragma unroll
                for (int q = 0; q < MD; ++q) m[q] = fmaf(h, w2[q], m[q]);
            }
        }
        __syncthreads();
    }

    // ---- finish edge: m silu, coor MLP, cw + mi pool ----
    {
        #pragma unroll
        for (int q = 0; q < MD; ++q) m[q] = silu_f(eb2[q] + m[q]);

        float cwacc = cb2[0];
        #pragma unroll
        for (int ch = 0; ch < 4; ++ch) {         // cc = 16*ch .. 16*ch+15
            float hh[16];
            const float* cb1c = cb1 + 16 * ch;
            #pragma unroll
            for (int q = 0; q < 16; ++q) hh[q] = cb1c[q];
            #pragma unroll
            for (int i = 0; i < MD; ++i) {
                const float* wr = cw1 + i * CHID + 16 * ch;   // contiguous, uniform -> s_load
                #pragma unroll
                for (int q = 0; q < 16; ++q) hh[q] = fmaf(m[i], wr[q], hh[q]);
            }
            const float* cw2c = cw2 + 16 * ch;
            #pragma unroll
            for (int q = 0; q < 16; ++q) cwacc = fmaf(silu_f(hh[q]), cw2c[q], cwacc);
        }
        cwacc = fminf(fmaxf(cwacc, -2.f), 2.f);
        if (tid < 232) ub.e.cw[e] = cwacc;

        #pragma unroll
        for (int q = 0; q < MD; ++q) {
            float v = m[q];
            v += __shfl_xor(v, 1);
            v += __shfl_xor(v, 2);
            v += __shfl_xor(v, 4);
            if (k_e == 0 && tid < 232) ub.e.mi[n_e][q] = v;
        }
    }
    __syncthreads();

    // ---- coords update (87 lanes) ----
    if (tid < Nn * 3) {
        int n2 = tid / 3, cix = tid % 3;
        float acc = 0.f;
        for (int k2 = 0; k2 < Kq; ++k2) {
            int j2 = s_idx[n2][k2];
            float nrm = sqrtf(s_dk[n2][k2]);
            float rel = __fsub_rn(s_c[n2][cix], s_c[j2][cix]);
            float rn = rel / fmaxf(nrm, 1e-8f) * cscale;
            acc = fmaf(ub.e.cw[n2 * Kq + k2], rn, acc);
        }
        coors_out[((size_t)b * Nn + n2) * 3 + cix] = s_c[n2][cix] + acc;
    }
    __syncthreads();   // uPQ -> ni transition (edge phase fully done)

    // ---- parallel LayerNorm + node-input build: 8 lanes per node ----
    if (tid < Nn * Kq) {
        const int g = tid >> 3, l = tid & 7;
        const float* fr = s_f[g];
        float4 a = *(const float4*)&fr[8 * l];
        float4 b4 = *(const float4*)&fr[8 * l + 4];
        float ps = ((a.x + a.y) + (a.z + a.w)) + ((b4.x + b4.y) + (b4.z + b4.w));
        ps += __shfl_xor(ps, 1); ps += __shfl_xor(ps, 2); ps += __shfl_xor(ps, 4);
        float mu = ps * (1.0f / 64.0f);
        float t0, pv = 0.f;
        t0 = a.x - mu;  pv = fmaf(t0, t0, pv);  t0 = a.y - mu;  pv = fmaf(t0, t0, pv);
        t0 = a.z - mu;  pv = fmaf(t0, t0, pv);  t0 = a.w - mu;  pv = fmaf(t0, t0, pv);
        t0 = b4.x - mu; pv = fmaf(t0, t0, pv);  t0 = b4.y - mu; pv = fmaf(t0, t0, pv);
        t0 = b4.z - mu; pv = fmaf(t0, t0, pv);  t0 = b4.w - mu; pv = fmaf(t0, t0, pv);
        pv += __shfl_xor(pv, 1); pv += __shfl_xor(pv, 2); pv += __shfl_xor(pv, 4);
        float rs = rsqrtf(pv * (1.0f / 64.0f) + 1e-5f);
        #pragma unroll
        for (int u = 0; u < 8; ++u) {
            int d = 8 * l + u;
            s_ni[g * NIN + d] = (fr[d] - mu) * rs * lng[d] + lnb[d];
        }
        if (l < 2) {
            #pragma unroll
            for (int u = 0; u < 8; ++u)
                s_ni[g * NIN + DIMq + 8 * l + u] = ub.e.mi[g][8 * l + u];
        }
    }
    __syncthreads();

    // ---- node MLP hidden ----
    for (int o = tid; o < Nn * NHID; o += 256) {
        int n2 = o >> 7, c = o & 127;
        float acc = nb1[c];
        const float* nir = s_ni + n2 * NIN;
        const float* w = nw1 + c;
        #pragma unroll 4
        for (int ig = 0; ig < 20; ++ig) {
            float4 f4 = *(const float4*)(nir + 4 * ig);
            acc = fmaf(f4.x, w[(4 * ig + 0) * NHID], acc);
            acc = fmaf(f4.y, w[(4 * ig + 1) * NHID], acc);
            acc = fmaf(f4.z, w[(4 * ig + 2) * NHID], acc);
            acc = fmaf(f4.w, w[(4 * ig + 3) * NHID], acc);
        }
        s_nh[n2 * NHID + c] = silu_f(acc);
    }
    __syncthreads();

    // ---- node MLP out + residual ----
    for (int o = tid; o < Nn * DIMq; o += 256) {
        int n2 = o >> 6, c = o & 63;
        float acc = nb2[c];
        const float* nhr = s_nh + n2 * NHID;
        const float* w = nw2 + c;
        #pragma unroll 4
        for (int ig = 0; ig < 32; ++ig) {
            float4 f4 = *(const float4*)(nhr + 4 * ig);
            acc = fmaf(f4.x, w[(4 * ig + 0) * DIMq], acc);
            acc = fmaf(f4.y, w[(4 * ig + 1) * DIMq], acc);
            acc = fmaf(f4.z, w[(4 * ig + 2) * DIMq], acc);
            acc = fmaf(f4.w, w[(4 * ig + 3) * DIMq], acc);
        }
        feats_out[((size_t)b * Nn + n2) * DIMq + c] = acc + s_f[n2][c];
    }
}

__global__ __launch_bounds__(64)
void k_read(const float* __restrict__ feats,
            const float* __restrict__ rw1, const float* __restrict__ rb1,
            const float* __restrict__ rw2, const float* __restrict__ rb2,
            float* __restrict__ out) {
    __shared__ float s_mol[DIMq];
    const int b = blockIdx.x, t = threadIdx.x;
    float acc = 0.f;
    for (int n = 0; n < Nn; ++n) acc += feats[((size_t)b * Nn + n) * DIMq + t];
    s_mol[t] = acc / 29.0f;
    __syncthreads();
    float a2 = rb1[t];
    for (int i = 0; i < DIMq; ++i) a2 = fmaf(s_mol[i], rw1[i * DIMq + t], a2);
    float part = silu_f(a2) * rw2[t];
    #pragma unroll
    for (int off = 32; off > 0; off >>= 1) part += __shfl_down(part, off);
    if (t == 0) out[b] = part + rb2[0];
}

extern "C" void kernel_launch(void* const* d_in, const int* in_sizes, int n_in,
                              void* d_out, int out_size, void* d_ws, size_t ws_size,
                              hipStream_t stream) {
    const int*   tokens = (const int*)d_in[0];
    const float* coords = (const float*)d_in[1];
    // d_in[2] = mask : all-True in this problem
    const float* temb = (const float*)d_in[3];
    const float* pemb = (const float*)d_in[4];
    const float* ew1 = (const float*)d_in[5];
    const float* eb1 = (const float*)d_in[6];
    const float* ew2 = (const float*)d_in[7];
    const float* eb2 = (const float*)d_in[8];
    const float* cw1 = (const float*)d_in[9];
    const float* cb1 = (const float*)d_in[10];
    const float* cw2 = (const float*)d_in[11];
    const float* cb2 = (const float*)d_in[12];
    const float* csc = (const float*)d_in[13];
    const float* lng = (const float*)d_in[14];
    const float* lnb = (const float*)d_in[15];
    const float* nw1 = (const float*)d_in[16];
    const float* nb1 = (const float*)d_in[17];
    const float* nw2 = (const float*)d_in[18];
    const float* nb2 = (const float*)d_in[19];
    const float* rw1 = (const float*)d_in[20];
    const float* rb1 = (const float*)d_in[21];
    const float* rw2 = (const float*)d_in[22];
    const float* rb2 = (const float*)d_in[23];

    float* fA = (float*)d_ws;
    float* fB = fA + (size_t)Bq * Nn * DIMq;
    float* cA = fB + (size_t)Bq * Nn * DIMq;
    float* cB = cA + (size_t)Bq * Nn * 3;

    k_init<<<(Bq * Nn * DIMq + 255) / 256, 256, 0, stream>>>(tokens, temb, pemb, fA);

    const float* fin = fA;
    const float* cin = coords;
    float* fbufs[2] = {fB, fA};
    float* cbufs[2] = {cA, cB};
    for (int l = 0; l < DEPTHq; ++l) {
        float* fout = fbufs[l & 1];
        float* cout = cbufs[l & 1];
        k_layer<<<Bq, 256, 0, stream>>>(fin, cin, fout, cout,
                                        ew1, eb1, ew2, eb2,
                                        cw1, cb1, cw2, cb2, csc,
                                        lng, lnb, nw1, nb1, nw2, nb2, l);
        fin = fout;
        cin = cout;
    }

    k_read<<<Bq, 64, 0, stream>>>(fin, rw1, rb1, rw2, rb2, (float*)d_out);
}